// Round 17
// baseline (1221.993 us; speedup 1.0000x reference)
//
#include <hip/hip_runtime.h>
#include <hip/hip_bf16.h>
#include <math.h>

#define H 450
#define HP 464            // padded row stride (bf16 elems; 928B, 16B-aligned)
#define KP 480            // padded K extent: 15 MFMA chunks of 32
#define LAT 56
#define V 780
#define LW 24
#define NE 46
#define NF 23
#define SLOT (1024*HP)
#define SROWS 2048
#define QROWS (24*1024)
#define PROWS (47*1024)
#define PTGT  (23*1024)
#define QBLK 6144
#define XBSZ ((size_t)QROWS * HP)     // one X block, elems (HP stride)
#define BTROWS 5312                   // packed B^T rows

typedef __hip_bfloat16 bf16;
typedef __attribute__((ext_vector_type(8))) short short8;
typedef __attribute__((ext_vector_type(4))) float f32x4;

#define MFMA16(a,b,c) __builtin_amdgcn_mfma_f32_16x16x32_bf16(a,b,c,0,0,0)

__device__ __forceinline__ float sigm_f(float x) { return 1.f / (1.f + __expf(-x)); }
__device__ __forceinline__ float tanh_f(float x) { return 2.f / (1.f + __expf(-2.f * x)) - 1.f; }
__device__ __forceinline__ float toF(bf16 x) { return __bfloat162float(x); }
__device__ __forceinline__ void stV(float* p, float v) { *p = v; }
__device__ __forceinline__ void stV(bf16* p, float v) { *p = __float2bfloat16(v); }
__device__ __forceinline__ short8 ld8(const bf16* p) { return *reinterpret_cast<const short8*>(p); }

// async global->LDS (kept for gemm128 staging where it is measured-good)
__device__ __forceinline__ void gl_lds(const bf16* g, bf16* l) {
    __builtin_amdgcn_global_load_lds(
        (const __attribute__((address_space(1))) void*)g,
        (__attribute__((address_space(3))) void*)l, 16, 0, 0);
}

// 128-tile XCD swizzle
__device__ __forceinline__ void xcd_decode128(int b, int C, int& row0, int& col0) {
    int rres = b & 7;
    int colt = (b >> 3) % C;
    int g    = b / (8 * C);
    row0 = (rres + 8 * g) * 128;
    col0 = colt * 128;
}

// ---------------------------------------------------------------------------
// Fused weight prep: pack all B^T panels (5312 rows x KP) in one launch.
// Layout: [BT4 1856 | Wzb 512 | Whb 512 | Ur 512 | Ub 512 | Wtop 512 | Wo 896]
__global__ __launch_bounds__(256)
void prep_w(const float* __restrict__ Wz, const float* __restrict__ Wh,
            const float* __restrict__ Wr, const float* __restrict__ Uw,
            const float* __restrict__ Ww, const float* __restrict__ Wo,
            const float* __restrict__ Ur, bf16* __restrict__ BT) {
    int idx = blockIdx.x * 256 + threadIdx.x;
    if (idx >= BTROWS * KP) return;
    int r = idx / KP, k = idx - r * KP;
    const float* src; int n; int N = H; int ld = H;
    if (r < 1856) {
        if (r < 450)       { src = Wz; n = r; }
        else if (r < 900)  { src = Wh; n = r - 450; }
        else if (r < 1350) { src = Wr; n = r - 900; }
        else               { src = Uw; n = r - 1350; }
    } else if (r < 2368) { src = Wz + 450 * 450; n = r - 1856; }
    else if (r < 2880)   { src = Wh + 450 * 450; n = r - 2368; }
    else if (r < 3392)   { src = Ur;             n = r - 2880; }
    else if (r < 3904)   { src = Uw + 450 * 450; n = r - 3392; }
    else if (r < 4416)   { src = Ww;             n = r - 3904; }
    else                 { src = Wo; n = r - 4416; N = V; ld = V; }
    float v = (n < N && k < H) ? src[(size_t)k * ld + n] : 0.f;
    BT[idx] = __float2bfloat16(v);
}

// bias4 pack + out zero (one tiny launch)
__global__ __launch_bounds__(256)
void pack_misc(const float* __restrict__ zb, const float* __restrict__ hb,
               const float* __restrict__ rb, float* __restrict__ bias4,
               float* __restrict__ out) {
    int i = blockIdx.x * 256 + threadIdx.x;
    if (i < 4) out[i] = 0.f;
    if (i >= 1856) return;
    float v = 0.f;
    if (i < 450)       v = zb[i];
    else if (i < 900)  v = hb[i - 450];
    else if (i < 1350) v = rb[i - 900];
    bias4[i] = v;
}

// x_all[t*1024+n][h] = emb[wid[n][t]][h]  (bf16, stride HP)
__global__ __launch_bounds__(256)
void gather_x(const float* __restrict__ emb, const int* __restrict__ wid,
              bf16* __restrict__ x_all) {
    int e = blockIdx.x * 256 + threadIdx.x;
    if (e >= 24 * 1024 * 225) return;
    int row = e / 225, h2 = e - row * 225;
    int t = row >> 10, n = row & 1023;
    int v = wid[n * LW + t];
    float2 x = ((const float2*)(emb + (size_t)v * H))[h2];
    bf16* dst = x_all + (size_t)row * HP + 2 * h2;
    dst[0] = __float2bfloat16(x.x);
    dst[1] = __float2bfloat16(x.y);
}

// ---------------------------------------------------------------------------
// LDS-staged GEMM: 128x128 tile, BK=32, global_load_lds + rotate swizzle
// ---------------------------------------------------------------------------
template<typename TC>
__global__ __launch_bounds__(256)
void gemm128(const bf16* __restrict__ A, int lda,
             const bf16* __restrict__ Bt, int N, int cblk,
             TC* __restrict__ C, int ldc,
             const float* __restrict__ bias,
             const float* __restrict__ addrow, int addld, int relu) {
    __shared__ bf16 As[128 * 32];
    __shared__ bf16 Bs[128 * 32];
    int tid = threadIdx.x;
    int lane = tid & 63, wave = tid >> 6;
    int wx = wave & 1, wy = wave >> 1;
    int lrow = lane & 15, quad = lane >> 4;
    int perm = ((quad + (lrow >> 1)) & 3) * 8;
    int row0, col0;
    xcd_decode128(blockIdx.x, cblk, row0, col0);
    f32x4 acc[4][4] = {};
    for (int k0i = 0; k0i < 15; k0i++) {
        int k0 = k0i * 32;
#pragma unroll
        for (int r = 0; r < 2; r++) {
            int tt = r * 256 + tid;
            int row = tt >> 2, cl = tt & 3;
            int cg = (cl - (row >> 1)) & 3;
            gl_lds(A  + (size_t)(row0 + row) * lda + k0 + cg * 8, As + tt * 8);
            gl_lds(Bt + (size_t)(col0 + row) * KP  + k0 + cg * 8, Bs + tt * 8);
        }
        __syncthreads();
        short8 a[4], b[4];
#pragma unroll
        for (int f = 0; f < 4; f++)
            a[f] = ld8(As + (wy * 64 + f * 16 + lrow) * 32 + perm);
#pragma unroll
        for (int f = 0; f < 4; f++)
            b[f] = ld8(Bs + (wx * 64 + f * 16 + lrow) * 32 + perm);
#pragma unroll
        for (int fi = 0; fi < 4; fi++)
#pragma unroll
            for (int fj = 0; fj < 4; fj++)
                acc[fi][fj] = MFMA16(a[fi], b[fj], acc[fi][fj]);
        __syncthreads();
    }
#pragma unroll
    for (int fi = 0; fi < 4; fi++)
#pragma unroll
        for (int e = 0; e < 4; e++) {
            int r = row0 + wy * 64 + fi * 16 + quad * 4 + e;
#pragma unroll
            for (int fj = 0; fj < 4; fj++) {
                int c = col0 + wx * 64 + fj * 16 + lrow;
                if (c >= N) continue;
                float v = acc[fi][fj][e];
                if (bias) v += bias[c];
                if (addrow) v += addrow[(size_t)(r & 1023) * addld + c];
                if (relu) v = fmaxf(v, 0.f);
                stV(&C[(size_t)r * ldc + c], v);
            }
        }
}

// Fused pre-GEMM: X @ [Wz|Wh|Wr|Ua] (N=1800), demux into 4 X blocks (HP stride)
__global__ __launch_bounds__(256)
void gemm128_pre(const bf16* __restrict__ A,
                 const bf16* __restrict__ Bt,
                 bf16* __restrict__ X0,          // Xz; blocks stride XBSZ
                 const float* __restrict__ bias4) {
    __shared__ bf16 As[128 * 32];
    __shared__ bf16 Bs[128 * 32];
    int tid = threadIdx.x;
    int lane = tid & 63, wave = tid >> 6;
    int wx = wave & 1, wy = wave >> 1;
    int lrow = lane & 15, quad = lane >> 4;
    int perm = ((quad + (lrow >> 1)) & 3) * 8;
    int row0, col0;
    xcd_decode128(blockIdx.x, 15, row0, col0);
    f32x4 acc[4][4] = {};
    for (int k0i = 0; k0i < 15; k0i++) {
        int k0 = k0i * 32;
#pragma unroll
        for (int r = 0; r < 2; r++) {
            int tt = r * 256 + tid;
            int row = tt >> 2, cl = tt & 3;
            int cg = (cl - (row >> 1)) & 3;
            gl_lds(A  + (size_t)(row0 + row) * HP + k0 + cg * 8, As + tt * 8);
            gl_lds(Bt + (size_t)(col0 + row) * KP + k0 + cg * 8, Bs + tt * 8);
        }
        __syncthreads();
        short8 a[4], b[4];
#pragma unroll
        for (int f = 0; f < 4; f++)
            a[f] = ld8(As + (wy * 64 + f * 16 + lrow) * 32 + perm);
#pragma unroll
        for (int f = 0; f < 4; f++)
            b[f] = ld8(Bs + (wx * 64 + f * 16 + lrow) * 32 + perm);
#pragma unroll
        for (int fi = 0; fi < 4; fi++)
#pragma unroll
            for (int fj = 0; fj < 4; fj++)
                acc[fi][fj] = MFMA16(a[fi], b[fj], acc[fi][fj]);
        __syncthreads();
    }
#pragma unroll
    for (int fi = 0; fi < 4; fi++)
#pragma unroll
        for (int e = 0; e < 4; e++) {
            int r = row0 + wy * 64 + fi * 16 + quad * 4 + e;
#pragma unroll
            for (int fj = 0; fj < 4; fj++) {
                int c = col0 + wx * 64 + fj * 16 + lrow;
                if (c >= 1800) continue;
                int mm = c / 450;
                int cc = c - mm * 450;
                float v = acc[fi][fj][e] + bias4[c];
                X0[(size_t)mm * XBSZ + (size_t)r * HP + cc] = __float2bfloat16(v);
            }
        }
}

// p GEMM, staged+swizzled: hs @ Ub; epilogue relu(+XUa[dst]+Ptv) dot Us -> pl
__global__ __launch_bounds__(256)
void p_gemm128(const bf16* __restrict__ hs, const bf16* __restrict__ UbT,
               const bf16* __restrict__ XUa, const float* __restrict__ Ptv,
               const float* __restrict__ Us, float* __restrict__ pl) {
    __shared__ bf16 As[128 * 32];
    __shared__ bf16 Bs[128 * 32];
    int tid = threadIdx.x;
    int lane = tid & 63, wave = tid >> 6;
    int wx = wave & 1, wy = wave >> 1;
    int lrow = lane & 15, quad = lane >> 4;
    int perm = ((quad + (lrow >> 1)) & 3) * 8;
    int row0, col0;
    xcd_decode128(blockIdx.x, 4, row0, col0);
    f32x4 acc[4][4] = {};
    for (int k0i = 0; k0i < 15; k0i++) {
        int k0 = k0i * 32;
#pragma unroll
        for (int r = 0; r < 2; r++) {
            int tt = r * 256 + tid;
            int row = tt >> 2, cl = tt & 3;
            int cg = (cl - (row >> 1)) & 3;
            gl_lds(hs  + (size_t)(row0 + row) * HP + k0 + cg * 8, As + tt * 8);
            gl_lds(UbT + (size_t)(col0 + row) * KP + k0 + cg * 8, Bs + tt * 8);
        }
        __syncthreads();
        short8 a[4], b[4];
#pragma unroll
        for (int f = 0; f < 4; f++)
            a[f] = ld8(As + (wy * 64 + f * 16 + lrow) * 32 + perm);
#pragma unroll
        for (int f = 0; f < 4; f++)
            b[f] = ld8(Bs + (wx * 64 + f * 16 + lrow) * 32 + perm);
#pragma unroll
        for (int fi = 0; fi < 4; fi++)
#pragma unroll
            for (int fj = 0; fj < 4; fj++)
                acc[fi][fj] = MFMA16(a[fi], b[fj], acc[fi][fj]);
        __syncthreads();
    }
#pragma unroll
    for (int fi = 0; fi < 4; fi++)
#pragma unroll
        for (int e = 0; e < 4; e++) {
            int r = row0 + wy * 64 + fi * 16 + quad * 4 + e;
            int t = r >> 10, n = r & 1023;
            int dst = (t < 23) ? (t + 1) : (45 - t);
            float part = 0.f;
#pragma unroll
            for (int fj = 0; fj < 4; fj++) {
                int c = col0 + wx * 64 + fj * 16 + lrow;
                if (c < H) {
                    float h = fmaxf(acc[fi][fj][e] + toF(XUa[((size_t)dst * 1024 + n) * HP + c])
                                    + Ptv[(size_t)n * H + c], 0.f);
                    part += h * Us[c];
                }
            }
#pragma unroll
            for (int off = 1; off < 16; off <<= 1)
                part += __shfl_xor(part, off);
            if (lrow == 0) atomicAdd(&pl[1024 + r], part);
        }
}

// Qtv/Ptv: out[n][c] = tv[n](56) @ Wlat(56x450) + bias[c]   grid(2,1024)
__global__ __launch_bounds__(256)
void tv_gemm(const float* __restrict__ tv, const float* __restrict__ Wlat,
             const float* __restrict__ bias, float* __restrict__ out) {
    int n = blockIdx.y;
    int c = blockIdx.x * 256 + threadIdx.x;
    __shared__ float tvs[LAT];
    if (threadIdx.x < LAT) tvs[threadIdx.x] = tv[n * LAT + threadIdx.x];
    __syncthreads();
    if (c < H) {
        float a = bias[c];
#pragma unroll 8
        for (int k = 0; k < LAT; k++) a += tvs[k] * Wlat[(size_t)k * H + c];
        out[(size_t)n * H + c] = a;
    }
}

// ---------------------------------------------------------------------------
// Barrier-free full scan, 16 waves/block, X staged via REGULAR vector loads
// (registers across k-loop, ds_write before barrier B). 128 blocks x 1024.
// ---------------------------------------------------------------------------
__global__ __launch_bounds__(1024)
void scan_full(bf16* __restrict__ hs,
               const bf16* __restrict__ WzbT, const bf16* __restrict__ WhbT,
               const bf16* __restrict__ UrT,
               const bf16* __restrict__ Xz, const bf16* __restrict__ Xh,
               const bf16* __restrict__ Xr) {
    __shared__ bf16 mnl[2][16][488];
    __shared__ bf16 rml[16][488];
    __shared__ bf16 xzs[16][464];
    __shared__ bf16 xhs[16][464];
    __shared__ bf16 xrs[16][464];
    int tid = threadIdx.x;
    int lane = tid & 63, w = tid >> 6;          // w in [0,16)
    int lrow = lane & 15, quad = lane >> 4;
    int row0 = blockIdx.x * 16;
    bool fwd = row0 < 1024;
    int nb = row0 & 1023;
    int f0 = w, f1 = w + 16;                    // f1 valid iff w < 13
    bool hasf1 = (f1 < 29);
    int crow = tid / 58, cj = tid - crow * 58;  // staging chunk (tid < 928)
    bool cok = tid < 928;
    float sreg[2][4];
#pragma unroll
    for (int i = 0; i < 2; i++)
#pragma unroll
        for (int e = 0; e < 4; e++) sreg[i][e] = 0.f;
    for (int i = tid; i < 2 * 16 * 488; i += 1024) ((bf16*)mnl)[i] = __float2bfloat16(0.f);
    for (int i = tid; i < 16 * 488; i += 1024) ((bf16*)rml)[i] = __float2bfloat16(0.f);
    __syncthreads();

    for (int u = 0; u < 23; u++) {
        int cur = u & 1, prev = cur ^ 1;
        int src = fwd ? u : 23 - u;
        int dst = fwd ? (u + 1) : (22 - u);
        // ---- issue X tile loads into registers (regular loads) ----
        float4 vz, vh, vr;
        if (cok) {
            vz = *reinterpret_cast<const float4*>(Xz + ((size_t)src * 1024 + nb + crow) * HP + cj * 8);
            vh = *reinterpret_cast<const float4*>(Xh + ((size_t)src * 1024 + nb + crow) * HP + cj * 8);
            if (u < 22)
                vr = *reinterpret_cast<const float4*>(Xr + ((size_t)dst * 1024 + nb + crow) * HP + cj * 8);
        }
        // ---- k1 k-loop: z_pre = m_prev@Wzb, h_pre = rm_prev@Whb ----
        f32x4 az[2], ah[2];
#pragma unroll
        for (int i = 0; i < 2; i++) {
            az[i] = (f32x4){0.f, 0.f, 0.f, 0.f};
            ah[i] = (f32x4){0.f, 0.f, 0.f, 0.f};
        }
        if (u > 0) {
            for (int k = 0; k < 15; k++) {
                short8 sA = *reinterpret_cast<const short8*>(&mnl[prev][lrow][k * 32 + quad * 8]);
                short8 rA = *reinterpret_cast<const short8*>(&rml[lrow][k * 32 + quad * 8]);
                {
                    short8 zB = ld8(WzbT + (size_t)(f0 * 16 + lrow) * KP + k * 32 + quad * 8);
                    short8 hB = ld8(WhbT + (size_t)(f0 * 16 + lrow) * KP + k * 32 + quad * 8);
                    az[0] = MFMA16(sA, zB, az[0]);
                    ah[0] = MFMA16(rA, hB, ah[0]);
                }
                if (hasf1) {
                    short8 zB = ld8(WzbT + (size_t)(f1 * 16 + lrow) * KP + k * 32 + quad * 8);
                    short8 hB = ld8(WhbT + (size_t)(f1 * 16 + lrow) * KP + k * 32 + quad * 8);
                    az[1] = MFMA16(sA, zB, az[1]);
                    ah[1] = MFMA16(rA, hB, ah[1]);
                }
            }
        }
        // ---- park staged X into LDS (after k-loop LDS reads are done issuing) ----
        if (cok) {
            *reinterpret_cast<float4*>(&xzs[crow][cj * 8]) = vz;
            *reinterpret_cast<float4*>(&xhs[crow][cj * 8]) = vh;
            if (u < 22)
                *reinterpret_cast<float4*>(&xrs[crow][cj * 8]) = vr;
        }
        __syncthreads();   // B: X staged; k-loop LDS reads complete

        // ---- k1 epilogue: state update (LDS X reads) ----
        int hsl = fwd ? u : 23 + u;
        bf16* hso = hs + (size_t)hsl * SLOT;
#pragma unroll
        for (int i = 0; i < 2; i++) {
            int f = (i == 0) ? f0 : f1;
            if (i == 1 && !hasf1) break;
            int c = f * 16 + lrow;
            if (c < H) {
#pragma unroll
                for (int e = 0; e < 4; e++) {
                    int rl = quad * 4 + e;
                    int n = (row0 + rl) & 1023;
                    float zp = az[i][e] + toF(xzs[rl][c]);
                    float hp = ah[i][e] + toF(xhs[rl][c]);
                    float z = sigm_f(zp), mt = tanh_f(hp);
                    float mn = (1.f - z) * sreg[i][e] + z * mt;
                    sreg[i][e] = mn;
                    bf16 mb = __float2bfloat16(mn);
                    mnl[cur][rl][c] = mb;
                    hso[(size_t)n * HP + c] = mb;
                }
            }
        }
        __syncthreads();   // C: mnl[cur] complete before k2 reads

        // ---- k2: r_pre = m_new@Ur + Xr[dst]; rml = sig(r_pre)*m_new ----
        if (u < 22) {
            f32x4 ar[2];
#pragma unroll
            for (int i = 0; i < 2; i++) ar[i] = (f32x4){0.f, 0.f, 0.f, 0.f};
            for (int k = 0; k < 15; k++) {
                short8 a = *reinterpret_cast<const short8*>(&mnl[cur][lrow][k * 32 + quad * 8]);
                ar[0] = MFMA16(a, ld8(UrT + (size_t)(f0 * 16 + lrow) * KP + k * 32 + quad * 8), ar[0]);
                if (hasf1)
                    ar[1] = MFMA16(a, ld8(UrT + (size_t)(f1 * 16 + lrow) * KP + k * 32 + quad * 8), ar[1]);
            }
#pragma unroll
            for (int i = 0; i < 2; i++) {
                int f = (i == 0) ? f0 : f1;
                if (i == 1 && !hasf1) break;
                int c = f * 16 + lrow;
                if (c < H) {
#pragma unroll
                    for (int e = 0; e < 4; e++) {
                        int rl = quad * 4 + e;
                        float rp = ar[i][e] + toF(xrs[rl][c]);
                        rml[rl][c] = __float2bfloat16(sigm_f(rp) * toF(mnl[cur][rl][c]));
                    }
                }
            }
            __syncthreads();  // A': rml complete; stage buffers free for next u
        }
    }
}

// hs[23+tl] += hs[21-tl] for tl in [0,22)
__global__ __launch_bounds__(256)
void hv_fixup(bf16* __restrict__ hs) {
    int idx = blockIdx.x * 256 + threadIdx.x;
    if (idx >= 22 * SLOT) return;
    int tl = idx / SLOT;
    int rem = idx - tl * SLOT;
    size_t a = (size_t)(23 + tl) * SLOT + rem;
    size_t b = (size_t)(21 - tl) * SLOT + rem;
    hs[a] = __float2bfloat16(toF(hs[a]) + toF(hs[b]));
}

// q_hidden root rows: relu(Qtv) -> qh rows 0..1023 (stride HP)
__global__ __launch_bounds__(256)
void q_root(const float* __restrict__ Qtv, bf16* __restrict__ qh) {
    int idx = blockIdx.x * 256 + threadIdx.x;
    if (idx >= 1024 * H) return;
    int n = idx / H, c = idx - n * H;
    qh[(size_t)n * HP + c] = __float2bfloat16(fmaxf(Qtv[idx], 0.f));
}

// q_reduce: wave-per-row online softmax + argmax -> per-block partials
__global__ __launch_bounds__(256)
void q_reduce(const float* __restrict__ ql, const int* __restrict__ wid,
              float* __restrict__ qred) {
    int wave = threadIdx.x >> 6, lane = threadIdx.x & 63;
    int r = blockIdx.x * 4 + wave;
    int t = r >> 10, n = r & 1023;
    int tgt = wid[n * LW + t];
    const float4* row4 = (const float4*)(ql + (size_t)r * V);
    float m = -3.4e38f, s = 0.f; int mi = 0x7fffffff;
#pragma unroll
    for (int k = 0; k < 4; k++) {
        int c4 = lane + 64 * k;
        if (c4 < 195) {
            float4 v4 = row4[c4];
            float vv[4] = {v4.x, v4.y, v4.z, v4.w};
#pragma unroll
            for (int e = 0; e < 4; e++) {
                float v = vv[e];
                if (v > m) { s = s * __expf(m - v) + 1.f; m = v; mi = c4 * 4 + e; }
                else s += __expf(v - m);
            }
        }
    }
#pragma unroll
    for (int off = 1; off < 64; off <<= 1) {
        float m2 = __shfl_xor(m, off);
        float s2 = __shfl_xor(s, off);
        int   i2 = __shfl_xor(mi, off);
        if (m2 > m || (m2 == m && i2 < mi)) {
            s = s2 + s * __expf(m - m2);
            m = m2; mi = i2;
        } else {
            s = s + s2 * __expf(m2 - m);
        }
    }
    __shared__ float lred[4][2];
    if (lane == 0) {
        float lse = m + logf(s);
        lred[wave][0] = lse - ql[(size_t)r * V + tgt];
        lred[wave][1] = (mi == tgt) ? 1.f : 0.f;
    }
    __syncthreads();
    if (threadIdx.x == 0) {
        qred[blockIdx.x * 2]     = lred[0][0] + lred[1][0] + lred[2][0] + lred[3][0];
        qred[blockIdx.x * 2 + 1] = lred[0][1] + lred[1][1] + lred[2][1] + lred[3][1];
    }
}

__global__ __launch_bounds__(256)
void q_final(const float* __restrict__ qred, float* __restrict__ out) {
    int tid = threadIdx.x;
    float L = 0.f, A = 0.f;
    for (int i = tid; i < QBLK; i += 256) { L += qred[2 * i]; A += qred[2 * i + 1]; }
    __shared__ float s1[256], s2[256];
    s1[tid] = L; s2[tid] = A;
    __syncthreads();
    for (int k = 128; k > 0; k >>= 1) {
        if (tid < k) { s1[tid] += s1[tid + k]; s2[tid] += s2[tid + k]; }
        __syncthreads();
    }
    if (tid == 0) {
        out[0] = s1[0] * (1.f / 1024.f);
        out[2] = s2[0] * (1.f / 24576.f);
    }
}

__global__ __launch_bounds__(256)
void p_init(float* __restrict__ pl, const float* __restrict__ Us_b) {
    int idx = blockIdx.x * 256 + threadIdx.x;
    if (idx < PROWS) pl[idx] = Us_b[0];
}

__global__ __launch_bounds__(256)
void p_root(const bf16* __restrict__ XUa, const float* __restrict__ Ptv,
            const float* __restrict__ Us, float* __restrict__ pl) {
    int n = blockIdx.x;
    int tid = threadIdx.x;
    const bf16* xa = XUa + (size_t)n * HP;
    const float* pt = Ptv + (size_t)n * H;
    float s = 0.f;
    for (int c = tid; c < H; c += 256)
        s += fmaxf(toF(xa[c]) + pt[c], 0.f) * Us[c];
    __shared__ float red[256];
    red[tid] = s;
    __syncthreads();
    for (int k = 128; k > 0; k >>= 1) {
        if (tid < k) red[tid] += red[tid + k];
        __syncthreads();
    }
    if (tid == 0) atomicAdd(&pl[n], red[0]);
}

// BCE loss + accuracy over 48128 rows; target = (r < 23552)
__global__ __launch_bounds__(256)
void p_final(const float* __restrict__ pl, float* __restrict__ out) {
    int r = blockIdx.x * 256 + threadIdx.x;
    int tid = threadIdx.x;
    float loss = 0.f, acc = 0.f;
    if (r < PROWS) {
        float l = pl[r];
        int tgt = (r < PTGT) ? 1 : 0;
        float x = tgt ? -l : l;
        loss = fmaxf(x, 0.f) + log1pf(expf(-fabsf(x)));
        int pred = (l > 0.f) ? 1 : 0;
        acc = (pred == tgt) ? 1.f : 0.f;
    }
    __shared__ float s1[256], s2[256];
    s1[tid] = loss; s2[tid] = acc;
    __syncthreads();
    for (int k = 128; k > 0; k >>= 1) {
        if (tid < k) { s1[tid] += s1[tid + k]; s2[tid] += s2[tid + k]; }
        __syncthreads();
    }
    if (tid == 0) {
        atomicAdd(&out[1], s1[0] * (1.f / 1024.f));
        atomicAdd(&out[3], s2[0] * (1.f / 48128.f));
    }
}

// ---------------------------------------------------------------------------
extern "C" void kernel_launch(void* const* d_in, const int* in_sizes, int n_in,
                              void* d_out, int out_size, void* d_ws, size_t ws_size,
                              hipStream_t stream) {
    const int*   wid  = (const int*)  d_in[0];
    const float* tv   = (const float*)d_in[1];
    const float* emb  = (const float*)d_in[2];
    const float* W_w  = (const float*)d_in[3];
    const float* W_b  = (const float*)d_in[4];
    const float* U_w  = (const float*)d_in[5];
    const float* U_b  = (const float*)d_in[6];
    const float* Wo_w = (const float*)d_in[7];
    const float* Wo_b = (const float*)d_in[8];
    const float* Us_w = (const float*)d_in[9];
    const float* Us_b = (const float*)d_in[10];
    const float* Wz_w = (const float*)d_in[11];
    const float* Wz_b = (const float*)d_in[12];
    const float* Wr_w = (const float*)d_in[13];
    const float* Ur_w = (const float*)d_in[14];
    const float* Ur_b = (const float*)d_in[15];
    const float* Wh_w = (const float*)d_in[16];
    const float* Wh_b = (const float*)d_in[17];
    float* out = (float*)d_out;

    // ---- workspace layout (~145 MiB) ----
    char* base = (char*)d_ws;
    const size_t XBb = XBSZ * 2;                         // bytes per X block
    bf16*  Xz   = (bf16*)(base);
    bf16*  Xh   = (bf16*)(base + XBb);
    bf16*  Xr   = (bf16*)(base + 2 * XBb);
    bf16*  XUa  = (bf16*)(base + 3 * XBb);
    bf16*  hs   = (bf16*)(base + 4 * XBb);               // 46 slots x 1024 x HP
    bf16*  x_all = hs;                                   // alias (dead before scan)
    char*  p1   = base + 4 * XBb + (size_t)NE * SLOT * 2;
    float* Qtv  = (float*)p1;               p1 += (size_t)1024 * H * 4;
    float* Ptv  = (float*)p1;               p1 += (size_t)1024 * H * 4;
    float* pl   = (float*)p1;               p1 += (size_t)PROWS * 4;
    float* qred = (float*)p1;               p1 += (size_t)QBLK * 2 * 4;
    float* bias4 = (float*)p1;              p1 += (size_t)1856 * 4;
    bf16*  BT   = (bf16*)p1;                             // BTROWS x KP
    bf16* BT4   = BT;
    bf16* WzbT  = BT + (size_t)1856 * KP;
    bf16* WhbT  = WzbT + (size_t)512 * KP;
    bf16* UrT   = WhbT + (size_t)512 * KP;
    bf16* UbT   = UrT  + (size_t)512 * KP;
    bf16* WtopT = UbT  + (size_t)512 * KP;
    bf16* WoT   = WtopT + (size_t)512 * KP;              // 896 rows
    // q-path aliases (used after p path completes):
    bf16*  qh = (bf16*)base;                             // 24576 x HP bf16
    float* ql = (float*)(base + (size_t)QROWS * HP * 2); // 24576 x 780 f32

    // ---- init + fused weight prep (2 launches) ----
    pack_misc<<<8, 256, 0, stream>>>(Wz_b, Wh_b, Ur_b, bias4, out);
    prep_w<<<(BTROWS * KP + 255) / 256, 256, 0, stream>>>(Wz_w, Wh_w, Wr_w, U_w,
                                                          W_w, Wo_w, Ur_w, BT);

    // ---- embedding gather + fused per-node precompute (one GEMM, N=1800) ----
    gather_x<<<(24 * 1024 * 225 + 255) / 256, 256, 0, stream>>>(emb, wid, x_all);
    gemm128_pre<<<(QROWS / 128) * 15, 256, 0, stream>>>(x_all, BT4, Xz, bias4);

    tv_gemm<<<dim3(2, 1024), 256, 0, stream>>>(tv, W_w + 450*450, W_b, Qtv);
    tv_gemm<<<dim3(2, 1024), 256, 0, stream>>>(tv, U_w + 900*450, U_b, Ptv);

    // ---- barrier-free full scan: one launch, 128 blocks x 1024 thr ----
    scan_full<<<SROWS / 16, 1024, 0, stream>>>(hs, WzbT, WhbT, UrT, Xz, Xh, Xr);
    hv_fixup<<<(22 * SLOT + 255) / 256, 256, 0, stream>>>(hs);

    // ---- p path (before q aliases X blocks / hs) ----
    p_init<<<(PROWS + 255) / 256, 256, 0, stream>>>(pl, Us_b);
    p_root<<<1024, 256, 0, stream>>>(XUa, Ptv, Us_w, pl);
    p_gemm128<<<(PROWS - 1024) / 128 * 4, 256, 0, stream>>>(hs, UbT, XUa, Ptv, Us_w, pl);
    p_final<<<PROWS / 256, 256, 0, stream>>>(pl, out);

    // ---- q path (qh over Xz; ql over Xh/Xr/XUa/hs-head) ----
    q_root<<<(1024 * H + 255) / 256, 256, 0, stream>>>(Qtv, qh);
    gemm128<bf16><<<(NF * 1024 / 128) * 4, 256, 0, stream>>>(hs, HP, WtopT, H, 4,
                                                             qh + (size_t)1024 * HP, HP,
                                                             (const float*)nullptr, Qtv, H, 1);
    gemm128<float><<<(QROWS / 128) * 7, 256, 0, stream>>>(qh, HP, WoT, V, 7, ql, V,
                                                          Wo_b, (const float*)nullptr, H, 0);
    q_reduce<<<QBLK, 256, 0, stream>>>(ql, wid, qred);
    q_final<<<1, 256, 0, stream>>>(qred, out);

    (void)in_sizes; (void)n_in; (void)out_size; (void)ws_size;
}

// Round 18
// 1006.987 us; speedup vs baseline: 1.2135x; 1.2135x over previous
//
#include <hip/hip_runtime.h>
#include <hip/hip_bf16.h>
#include <math.h>

#define H 450
#define HP 464            // padded A row stride (bf16 elems; 16B-aligned rows)
#define KP 480            // padded K extent: 15 MFMA chunks of 32
#define LAT 56
#define V 780
#define LW 24
#define NE 46
#define NF 23
#define SLOT (1024*HP)
#define SROWS 2048
#define QROWS (24*1024)
#define PROWS (47*1024)
#define PTGT  (23*1024)
#define QBLK 6144
#define XBSZ ((size_t)QROWS * H)      // one X block, elems (H stride — r16 layout)
#define BTROWS 5312                   // packed B^T rows

typedef __hip_bfloat16 bf16;
typedef __attribute__((ext_vector_type(8))) short short8;
typedef __attribute__((ext_vector_type(4))) short short4v;
typedef __attribute__((ext_vector_type(4))) float f32x4;

#define MFMA16(a,b,c) __builtin_amdgcn_mfma_f32_16x16x32_bf16(a,b,c,0,0,0)

__device__ __forceinline__ float sigm_f(float x) { return 1.f / (1.f + __expf(-x)); }
__device__ __forceinline__ float tanh_f(float x) { return 2.f / (1.f + __expf(-2.f * x)) - 1.f; }
__device__ __forceinline__ float toF(bf16 x) { return __bfloat162float(x); }
__device__ __forceinline__ float bf2f(short s) {
    unsigned u = ((unsigned)(unsigned short)s) << 16;
    return __uint_as_float(u);
}
__device__ __forceinline__ void stV(float* p, float v) { *p = v; }
__device__ __forceinline__ void stV(bf16* p, float v) { *p = __float2bfloat16(v); }
__device__ __forceinline__ short8 ld8(const bf16* p) { return *reinterpret_cast<const short8*>(p); }

// async global->LDS (gemm128 staging — measured-good there)
__device__ __forceinline__ void gl_lds(const bf16* g, bf16* l) {
    __builtin_amdgcn_global_load_lds(
        (const __attribute__((address_space(1))) void*)g,
        (__attribute__((address_space(3))) void*)l, 16, 0, 0);
}

// 128-tile XCD swizzle
__device__ __forceinline__ void xcd_decode128(int b, int C, int& row0, int& col0) {
    int rres = b & 7;
    int colt = (b >> 3) % C;
    int g    = b / (8 * C);
    row0 = (rres + 8 * g) * 128;
    col0 = colt * 128;
}

// ---------------------------------------------------------------------------
// Fused weight prep: pack all B^T panels (5312 rows x KP) in one launch.
// Layout: [BT4 1856 | Wzb 512 | Whb 512 | Ur 512 | Ub 512 | Wtop 512 | Wo 896]
__global__ __launch_bounds__(256)
void prep_w(const float* __restrict__ Wz, const float* __restrict__ Wh,
            const float* __restrict__ Wr, const float* __restrict__ Uw,
            const float* __restrict__ Ww, const float* __restrict__ Wo,
            const float* __restrict__ Ur, bf16* __restrict__ BT) {
    int idx = blockIdx.x * 256 + threadIdx.x;
    if (idx >= BTROWS * KP) return;
    int r = idx / KP, k = idx - r * KP;
    const float* src; int n; int N = H; int ld = H;
    if (r < 1856) {
        if (r < 450)       { src = Wz; n = r; }
        else if (r < 900)  { src = Wh; n = r - 450; }
        else if (r < 1350) { src = Wr; n = r - 900; }
        else               { src = Uw; n = r - 1350; }
    } else if (r < 2368) { src = Wz + 450 * 450; n = r - 1856; }
    else if (r < 2880)   { src = Wh + 450 * 450; n = r - 2368; }
    else if (r < 3392)   { src = Ur;             n = r - 2880; }
    else if (r < 3904)   { src = Uw + 450 * 450; n = r - 3392; }
    else if (r < 4416)   { src = Ww;             n = r - 3904; }
    else                 { src = Wo; n = r - 4416; N = V; ld = V; }
    float v = (n < N && k < H) ? src[(size_t)k * ld + n] : 0.f;
    BT[idx] = __float2bfloat16(v);
}

// bias4 pack + out zero
__global__ __launch_bounds__(256)
void pack_misc(const float* __restrict__ zb, const float* __restrict__ hb,
               const float* __restrict__ rb, float* __restrict__ bias4,
               float* __restrict__ out) {
    int i = blockIdx.x * 256 + threadIdx.x;
    if (i < 4) out[i] = 0.f;
    if (i >= 1856) return;
    float v = 0.f;
    if (i < 450)       v = zb[i];
    else if (i < 900)  v = hb[i - 450];
    else if (i < 1350) v = rb[i - 900];
    bias4[i] = v;
}

// x_all[t*1024+n][h] = emb[wid[n][t]][h]  (bf16, stride HP)
__global__ __launch_bounds__(256)
void gather_x(const float* __restrict__ emb, const int* __restrict__ wid,
              bf16* __restrict__ x_all) {
    int e = blockIdx.x * 256 + threadIdx.x;
    if (e >= 24 * 1024 * 225) return;
    int row = e / 225, h2 = e - row * 225;
    int t = row >> 10, n = row & 1023;
    int v = wid[n * LW + t];
    float2 x = ((const float2*)(emb + (size_t)v * H))[h2];
    bf16* dst = x_all + (size_t)row * HP + 2 * h2;
    dst[0] = __float2bfloat16(x.x);
    dst[1] = __float2bfloat16(x.y);
}

// ---------------------------------------------------------------------------
// LDS-staged GEMM: 128x128 tile, BK=32, global_load_lds + rotate swizzle
// ---------------------------------------------------------------------------
template<typename TC>
__global__ __launch_bounds__(256)
void gemm128(const bf16* __restrict__ A, int lda,
             const bf16* __restrict__ Bt, int N, int cblk,
             TC* __restrict__ C, int ldc,
             const float* __restrict__ bias,
             const float* __restrict__ addrow, int addld, int relu) {
    __shared__ bf16 As[128 * 32];
    __shared__ bf16 Bs[128 * 32];
    int tid = threadIdx.x;
    int lane = tid & 63, wave = tid >> 6;
    int wx = wave & 1, wy = wave >> 1;
    int lrow = lane & 15, quad = lane >> 4;
    int perm = ((quad + (lrow >> 1)) & 3) * 8;
    int row0, col0;
    xcd_decode128(blockIdx.x, cblk, row0, col0);
    f32x4 acc[4][4] = {};
    for (int k0i = 0; k0i < 15; k0i++) {
        int k0 = k0i * 32;
#pragma unroll
        for (int r = 0; r < 2; r++) {
            int tt = r * 256 + tid;
            int row = tt >> 2, cl = tt & 3;
            int cg = (cl - (row >> 1)) & 3;
            gl_lds(A  + (size_t)(row0 + row) * lda + k0 + cg * 8, As + tt * 8);
            gl_lds(Bt + (size_t)(col0 + row) * KP  + k0 + cg * 8, Bs + tt * 8);
        }
        __syncthreads();
        short8 a[4], b[4];
#pragma unroll
        for (int f = 0; f < 4; f++)
            a[f] = ld8(As + (wy * 64 + f * 16 + lrow) * 32 + perm);
#pragma unroll
        for (int f = 0; f < 4; f++)
            b[f] = ld8(Bs + (wx * 64 + f * 16 + lrow) * 32 + perm);
#pragma unroll
        for (int fi = 0; fi < 4; fi++)
#pragma unroll
            for (int fj = 0; fj < 4; fj++)
                acc[fi][fj] = MFMA16(a[fi], b[fj], acc[fi][fj]);
        __syncthreads();
    }
#pragma unroll
    for (int fi = 0; fi < 4; fi++)
#pragma unroll
        for (int e = 0; e < 4; e++) {
            int r = row0 + wy * 64 + fi * 16 + quad * 4 + e;
#pragma unroll
            for (int fj = 0; fj < 4; fj++) {
                int c = col0 + wx * 64 + fj * 16 + lrow;
                if (c >= N) continue;
                float v = acc[fi][fj][e];
                if (bias) v += bias[c];
                if (addrow) v += addrow[(size_t)(r & 1023) * addld + c];
                if (relu) v = fmaxf(v, 0.f);
                stV(&C[(size_t)r * ldc + c], v);
            }
        }
}

// Fused pre-GEMM: X @ [Wz|Wh|Wr|Ua] (N=1800), demux epilogue into 4 X blocks
__global__ __launch_bounds__(256)
void gemm128_pre(const bf16* __restrict__ A,
                 const bf16* __restrict__ Bt,
                 bf16* __restrict__ X0,          // Xz; blocks stride XBSZ
                 const float* __restrict__ bias4) {
    __shared__ bf16 As[128 * 32];
    __shared__ bf16 Bs[128 * 32];
    int tid = threadIdx.x;
    int lane = tid & 63, wave = tid >> 6;
    int wx = wave & 1, wy = wave >> 1;
    int lrow = lane & 15, quad = lane >> 4;
    int perm = ((quad + (lrow >> 1)) & 3) * 8;
    int row0, col0;
    xcd_decode128(blockIdx.x, 15, row0, col0);
    f32x4 acc[4][4] = {};
    for (int k0i = 0; k0i < 15; k0i++) {
        int k0 = k0i * 32;
#pragma unroll
        for (int r = 0; r < 2; r++) {
            int tt = r * 256 + tid;
            int row = tt >> 2, cl = tt & 3;
            int cg = (cl - (row >> 1)) & 3;
            gl_lds(A  + (size_t)(row0 + row) * HP + k0 + cg * 8, As + tt * 8);
            gl_lds(Bt + (size_t)(col0 + row) * KP + k0 + cg * 8, Bs + tt * 8);
        }
        __syncthreads();
        short8 a[4], b[4];
#pragma unroll
        for (int f = 0; f < 4; f++)
            a[f] = ld8(As + (wy * 64 + f * 16 + lrow) * 32 + perm);
#pragma unroll
        for (int f = 0; f < 4; f++)
            b[f] = ld8(Bs + (wx * 64 + f * 16 + lrow) * 32 + perm);
#pragma unroll
        for (int fi = 0; fi < 4; fi++)
#pragma unroll
            for (int fj = 0; fj < 4; fj++)
                acc[fi][fj] = MFMA16(a[fi], b[fj], acc[fi][fj]);
        __syncthreads();
    }
#pragma unroll
    for (int fi = 0; fi < 4; fi++)
#pragma unroll
        for (int e = 0; e < 4; e++) {
            int r = row0 + wy * 64 + fi * 16 + quad * 4 + e;
#pragma unroll
            for (int fj = 0; fj < 4; fj++) {
                int c = col0 + wx * 64 + fj * 16 + lrow;
                if (c >= 1800) continue;
                int mm = c / 450;
                int cc = c - mm * 450;
                float v = acc[fi][fj][e] + bias4[c];
                X0[(size_t)mm * XBSZ + (size_t)r * H + cc] = __float2bfloat16(v);
            }
        }
}

// p GEMM: hs @ Ub; epilogue relu(+XUa[dst]+Ptv) dot Us -> atomicAdd pl
__global__ __launch_bounds__(256)
void p_gemm128(const bf16* __restrict__ hs, const bf16* __restrict__ UbT,
               const bf16* __restrict__ XUa, const float* __restrict__ Ptv,
               const float* __restrict__ Us, float* __restrict__ pl) {
    __shared__ bf16 As[128 * 32];
    __shared__ bf16 Bs[128 * 32];
    int tid = threadIdx.x;
    int lane = tid & 63, wave = tid >> 6;
    int wx = wave & 1, wy = wave >> 1;
    int lrow = lane & 15, quad = lane >> 4;
    int perm = ((quad + (lrow >> 1)) & 3) * 8;
    int row0, col0;
    xcd_decode128(blockIdx.x, 4, row0, col0);
    f32x4 acc[4][4] = {};
    for (int k0i = 0; k0i < 15; k0i++) {
        int k0 = k0i * 32;
#pragma unroll
        for (int r = 0; r < 2; r++) {
            int tt = r * 256 + tid;
            int row = tt >> 2, cl = tt & 3;
            int cg = (cl - (row >> 1)) & 3;
            gl_lds(hs  + (size_t)(row0 + row) * HP + k0 + cg * 8, As + tt * 8);
            gl_lds(UbT + (size_t)(col0 + row) * KP + k0 + cg * 8, Bs + tt * 8);
        }
        __syncthreads();
        short8 a[4], b[4];
#pragma unroll
        for (int f = 0; f < 4; f++)
            a[f] = ld8(As + (wy * 64 + f * 16 + lrow) * 32 + perm);
#pragma unroll
        for (int f = 0; f < 4; f++)
            b[f] = ld8(Bs + (wx * 64 + f * 16 + lrow) * 32 + perm);
#pragma unroll
        for (int fi = 0; fi < 4; fi++)
#pragma unroll
            for (int fj = 0; fj < 4; fj++)
                acc[fi][fj] = MFMA16(a[fi], b[fj], acc[fi][fj]);
        __syncthreads();
    }
#pragma unroll
    for (int fi = 0; fi < 4; fi++)
#pragma unroll
        for (int e = 0; e < 4; e++) {
            int r = row0 + wy * 64 + fi * 16 + quad * 4 + e;
            int t = r >> 10, n = r & 1023;
            int dst = (t < 23) ? (t + 1) : (45 - t);
            float part = 0.f;
#pragma unroll
            for (int fj = 0; fj < 4; fj++) {
                int c = col0 + wx * 64 + fj * 16 + lrow;
                if (c < H) {
                    float h = fmaxf(acc[fi][fj][e] + toF(XUa[((size_t)dst * 1024 + n) * H + c])
                                    + Ptv[(size_t)n * H + c], 0.f);
                    part += h * Us[c];
                }
            }
#pragma unroll
            for (int off = 1; off < 16; off <<= 1)
                part += __shfl_xor(part, off);
            if (lrow == 0) atomicAdd(&pl[1024 + r], part);
        }
}

// Qtv/Ptv: out[n][c] = tv[n](56) @ Wlat(56x450) + bias[c]   grid(2,1024)
__global__ __launch_bounds__(256)
void tv_gemm(const float* __restrict__ tv, const float* __restrict__ Wlat,
             const float* __restrict__ bias, float* __restrict__ out) {
    int n = blockIdx.y;
    int c = blockIdx.x * 256 + threadIdx.x;
    __shared__ float tvs[LAT];
    if (threadIdx.x < LAT) tvs[threadIdx.x] = tv[n * LAT + threadIdx.x];
    __syncthreads();
    if (c < H) {
        float a = bias[c];
#pragma unroll 8
        for (int k = 0; k < LAT; k++) a += tvs[k] * Wlat[(size_t)k * H + c];
        out[(size_t)n * H + c] = a;
    }
}

// ---------------------------------------------------------------------------
// Barrier-free full scan, 16 waves/block (r16 EXACT structure — scattered X
// reads + scattered hs writes are load-bearing for L2/L3 residency).
// ---------------------------------------------------------------------------
__global__ __launch_bounds__(1024)
void scan_full(bf16* __restrict__ hs,
               const bf16* __restrict__ WzbT, const bf16* __restrict__ WhbT,
               const bf16* __restrict__ UrT,
               const bf16* __restrict__ Xz, const bf16* __restrict__ Xh,
               const bf16* __restrict__ Xr) {
    __shared__ bf16 mnl[2][16][488];
    __shared__ bf16 rml[16][488];
    int tid = threadIdx.x;
    int lane = tid & 63, w = tid >> 6;          // w in [0,16)
    int lrow = lane & 15, quad = lane >> 4;
    int row0 = blockIdx.x * 16;
    bool fwd = row0 < 1024;
    int f0 = w, f1 = w + 16;                    // f1 valid iff w < 13
    bool hasf1 = (f1 < 29);
    float sreg[2][4];
#pragma unroll
    for (int i = 0; i < 2; i++)
#pragma unroll
        for (int e = 0; e < 4; e++) sreg[i][e] = 0.f;
    for (int i = tid; i < 2 * 16 * 488; i += 1024) ((bf16*)mnl)[i] = __float2bfloat16(0.f);
    for (int i = tid; i < 16 * 488; i += 1024) ((bf16*)rml)[i] = __float2bfloat16(0.f);
    __syncthreads();

    for (int u = 0; u < 23; u++) {
        int cur = u & 1, prev = cur ^ 1;
        // ---- k1: z_pre = m_prev@Wzb, h_pre = rm_prev@Whb ----
        f32x4 az[2], ah[2];
#pragma unroll
        for (int i = 0; i < 2; i++) {
            az[i] = (f32x4){0.f, 0.f, 0.f, 0.f};
            ah[i] = (f32x4){0.f, 0.f, 0.f, 0.f};
        }
        if (u > 0) {
            for (int k = 0; k < 15; k++) {
                short8 sA = *reinterpret_cast<const short8*>(&mnl[prev][lrow][k * 32 + quad * 8]);
                short8 rA = *reinterpret_cast<const short8*>(&rml[lrow][k * 32 + quad * 8]);
                {
                    short8 zB = ld8(WzbT + (size_t)(f0 * 16 + lrow) * KP + k * 32 + quad * 8);
                    short8 hB = ld8(WhbT + (size_t)(f0 * 16 + lrow) * KP + k * 32 + quad * 8);
                    az[0] = MFMA16(sA, zB, az[0]);
                    ah[0] = MFMA16(rA, hB, ah[0]);
                }
                if (hasf1) {
                    short8 zB = ld8(WzbT + (size_t)(f1 * 16 + lrow) * KP + k * 32 + quad * 8);
                    short8 hB = ld8(WhbT + (size_t)(f1 * 16 + lrow) * KP + k * 32 + quad * 8);
                    az[1] = MFMA16(sA, zB, az[1]);
                    ah[1] = MFMA16(rA, hB, ah[1]);
                }
            }
        }
        int src = fwd ? u : 23 - u;
        bf16* hso = hs + (size_t)(fwd ? u : 23 + u) * SLOT;
#pragma unroll
        for (int i = 0; i < 2; i++) {
            int f = (i == 0) ? f0 : f1;
            if (i == 1 && !hasf1) break;
            int c = f * 16 + lrow;
            if (c < H) {
#pragma unroll
                for (int e = 0; e < 4; e++) {
                    int rl = quad * 4 + e;
                    int n = (row0 + rl) & 1023;
                    float zp = az[i][e] + toF(Xz[((size_t)src * 1024 + n) * H + c]);
                    float hp = ah[i][e] + toF(Xh[((size_t)src * 1024 + n) * H + c]);
                    float z = sigm_f(zp), mt = tanh_f(hp);
                    float mn = (1.f - z) * sreg[i][e] + z * mt;
                    sreg[i][e] = mn;
                    bf16 mb = __float2bfloat16(mn);
                    mnl[cur][rl][c] = mb;
                    hso[(size_t)n * HP + c] = mb;
                }
            }
        }
        __syncthreads();   // mnl[cur] complete before k2 reads

        // ---- k2: r_pre = m_new@Ur + Xr[dst]; rml = sig(r_pre)*m_new ----
        if (u < 22) {
            f32x4 ar[2];
#pragma unroll
            for (int i = 0; i < 2; i++) ar[i] = (f32x4){0.f, 0.f, 0.f, 0.f};
            for (int k = 0; k < 15; k++) {
                short8 a = *reinterpret_cast<const short8*>(&mnl[cur][lrow][k * 32 + quad * 8]);
                ar[0] = MFMA16(a, ld8(UrT + (size_t)(f0 * 16 + lrow) * KP + k * 32 + quad * 8), ar[0]);
                if (hasf1)
                    ar[1] = MFMA16(a, ld8(UrT + (size_t)(f1 * 16 + lrow) * KP + k * 32 + quad * 8), ar[1]);
            }
            int dst = fwd ? (u + 1) : (22 - u);
#pragma unroll
            for (int i = 0; i < 2; i++) {
                int f = (i == 0) ? f0 : f1;
                if (i == 1 && !hasf1) break;
                int c = f * 16 + lrow;
                if (c < H) {
#pragma unroll
                    for (int e = 0; e < 4; e++) {
                        int rl = quad * 4 + e;
                        int n = (row0 + rl) & 1023;
                        float rp = ar[i][e] + toF(Xr[((size_t)dst * 1024 + n) * H + c]);
                        rml[rl][c] = __float2bfloat16(sigm_f(rp) * toF(mnl[cur][rl][c]));
                    }
                }
            }
            __syncthreads();  // rml complete before next k1 reads
        }
    }
}

// hs[23+tl] += hs[21-tl] for tl in [0,22)
__global__ __launch_bounds__(256)
void hv_fixup(bf16* __restrict__ hs) {
    int idx = blockIdx.x * 256 + threadIdx.x;
    if (idx >= 22 * SLOT) return;
    int tl = idx / SLOT;
    int rem = idx - tl * SLOT;
    size_t a = (size_t)(23 + tl) * SLOT + rem;
    size_t b = (size_t)(21 - tl) * SLOT + rem;
    hs[a] = __float2bfloat16(toF(hs[a]) + toF(hs[b]));
}

// q_hidden root rows: relu(Qtv) -> qh rows 0..1023 (stride HP)
__global__ __launch_bounds__(256)
void q_root(const float* __restrict__ Qtv, bf16* __restrict__ qh) {
    int idx = blockIdx.x * 256 + threadIdx.x;
    if (idx >= 1024 * H) return;
    int n = idx / H, c = idx - n * H;
    qh[(size_t)n * HP + c] = __float2bfloat16(fmaxf(Qtv[idx], 0.f));
}

// q_reduce (bf16 logits): wave-per-row online softmax + argmax
__global__ __launch_bounds__(256)
void q_reduce(const bf16* __restrict__ ql, const int* __restrict__ wid,
              float* __restrict__ qred) {
    int wave = threadIdx.x >> 6, lane = threadIdx.x & 63;
    int r = blockIdx.x * 4 + wave;
    int t = r >> 10, n = r & 1023;
    int tgt = wid[n * LW + t];
    const short4v* row4 = (const short4v*)(ql + (size_t)r * V);   // 195 chunks of 4
    float m = -3.4e38f, s = 0.f; int mi = 0x7fffffff;
#pragma unroll
    for (int k = 0; k < 4; k++) {
        int c4 = lane + 64 * k;
        if (c4 < 195) {
            short4v v4 = row4[c4];
#pragma unroll
            for (int e = 0; e < 4; e++) {
                float v = bf2f(v4[e]);
                if (v > m) { s = s * __expf(m - v) + 1.f; m = v; mi = c4 * 4 + e; }
                else s += __expf(v - m);
            }
        }
    }
#pragma unroll
    for (int off = 1; off < 64; off <<= 1) {
        float m2 = __shfl_xor(m, off);
        float s2 = __shfl_xor(s, off);
        int   i2 = __shfl_xor(mi, off);
        if (m2 > m || (m2 == m && i2 < mi)) {
            s = s2 + s * __expf(m - m2);
            m = m2; mi = i2;
        } else {
            s = s + s2 * __expf(m2 - m);
        }
    }
    __shared__ float lred[4][2];
    if (lane == 0) {
        float lse = m + logf(s);
        lred[wave][0] = lse - toF(ql[(size_t)r * V + tgt]);
        lred[wave][1] = (mi == tgt) ? 1.f : 0.f;
    }
    __syncthreads();
    if (threadIdx.x == 0) {
        qred[blockIdx.x * 2]     = lred[0][0] + lred[1][0] + lred[2][0] + lred[3][0];
        qred[blockIdx.x * 2 + 1] = lred[0][1] + lred[1][1] + lred[2][1] + lred[3][1];
    }
}

__global__ __launch_bounds__(256)
void q_final(const float* __restrict__ qred, float* __restrict__ out) {
    int tid = threadIdx.x;
    float L = 0.f, A = 0.f;
    for (int i = tid; i < QBLK; i += 256) { L += qred[2 * i]; A += qred[2 * i + 1]; }
    __shared__ float s1[256], s2[256];
    s1[tid] = L; s2[tid] = A;
    __syncthreads();
    for (int k = 128; k > 0; k >>= 1) {
        if (tid < k) { s1[tid] += s1[tid + k]; s2[tid] += s2[tid + k]; }
        __syncthreads();
    }
    if (tid == 0) {
        out[0] = s1[0] * (1.f / 1024.f);
        out[2] = s2[0] * (1.f / 24576.f);
    }
}

// p root rows: pl[n] = sum_c relu(XUa[0][n][c]+Ptv[n][c])*Us[c]  (plain store)
__global__ __launch_bounds__(256)
void p_root(const bf16* __restrict__ XUa, const float* __restrict__ Ptv,
            const float* __restrict__ Us, float* __restrict__ pl) {
    int n = blockIdx.x;
    int tid = threadIdx.x;
    const bf16* xa = XUa + (size_t)n * H;
    const float* pt = Ptv + (size_t)n * H;
    float s = 0.f;
    for (int c = tid; c < H; c += 256)
        s += fmaxf(toF(xa[c]) + pt[c], 0.f) * Us[c];
    __shared__ float red[256];
    red[tid] = s;
    __syncthreads();
    for (int k = 128; k > 0; k >>= 1) {
        if (tid < k) red[tid] += red[tid + k];
        __syncthreads();
    }
    if (tid == 0) pl[n] = red[0];
}

// BCE loss + accuracy; logit = pl[r] + Us_b[0]; target = (r < 23552)
__global__ __launch_bounds__(256)
void p_final(const float* __restrict__ pl, const float* __restrict__ Us_b,
             float* __restrict__ out) {
    int r = blockIdx.x * 256 + threadIdx.x;
    int tid = threadIdx.x;
    float ub = Us_b[0];
    float loss = 0.f, acc = 0.f;
    if (r < PROWS) {
        float l = pl[r] + ub;
        int tgt = (r < PTGT) ? 1 : 0;
        float x = tgt ? -l : l;
        loss = fmaxf(x, 0.f) + log1pf(expf(-fabsf(x)));
        int pred = (l > 0.f) ? 1 : 0;
        acc = (pred == tgt) ? 1.f : 0.f;
    }
    __shared__ float s1[256], s2[256];
    s1[tid] = loss; s2[tid] = acc;
    __syncthreads();
    for (int k = 128; k > 0; k >>= 1) {
        if (tid < k) { s1[tid] += s1[tid + k]; s2[tid] += s2[tid + k]; }
        __syncthreads();
    }
    if (tid == 0) {
        atomicAdd(&out[1], s1[0] * (1.f / 1024.f));
        atomicAdd(&out[3], s2[0] * (1.f / 48128.f));
    }
}

// ---------------------------------------------------------------------------
extern "C" void kernel_launch(void* const* d_in, const int* in_sizes, int n_in,
                              void* d_out, int out_size, void* d_ws, size_t ws_size,
                              hipStream_t stream) {
    const int*   wid  = (const int*)  d_in[0];
    const float* tv   = (const float*)d_in[1];
    const float* emb  = (const float*)d_in[2];
    const float* W_w  = (const float*)d_in[3];
    const float* W_b  = (const float*)d_in[4];
    const float* U_w  = (const float*)d_in[5];
    const float* U_b  = (const float*)d_in[6];
    const float* Wo_w = (const float*)d_in[7];
    const float* Wo_b = (const float*)d_in[8];
    const float* Us_w = (const float*)d_in[9];
    const float* Us_b = (const float*)d_in[10];
    const float* Wz_w = (const float*)d_in[11];
    const float* Wz_b = (const float*)d_in[12];
    const float* Wr_w = (const float*)d_in[13];
    const float* Ur_w = (const float*)d_in[14];
    const float* Ur_b = (const float*)d_in[15];
    const float* Wh_w = (const float*)d_in[16];
    const float* Wh_b = (const float*)d_in[17];
    float* out = (float*)d_out;

    // ---- workspace layout (~140 MiB, r16 layout) ----
    char* base = (char*)d_ws;
    const size_t XBb = XBSZ * 2;                         // bytes per X block
    bf16*  Xz   = (bf16*)(base);
    bf16*  Xh   = (bf16*)(base + XBb);
    bf16*  Xr   = (bf16*)(base + 2 * XBb);
    bf16*  XUa  = (bf16*)(base + 3 * XBb);
    bf16*  hs   = (bf16*)(base + 4 * XBb);               // 46 slots x 1024 x HP
    bf16*  x_all = hs;                                   // alias (dead before scan)
    char*  p1   = base + 4 * XBb + (size_t)NE * SLOT * 2;
    float* Qtv  = (float*)p1;               p1 += (size_t)1024 * H * 4;
    float* Ptv  = (float*)p1;               p1 += (size_t)1024 * H * 4;
    float* pl   = (float*)p1;               p1 += (size_t)PROWS * 4;
    float* qred = (float*)p1;               p1 += (size_t)QBLK * 2 * 4;
    float* bias4 = (float*)p1;              p1 += (size_t)1856 * 4;
    bf16*  BT   = (bf16*)p1;                             // BTROWS x KP
    bf16* BT4   = BT;
    bf16* WzbT  = BT + (size_t)1856 * KP;
    bf16* WhbT  = WzbT + (size_t)512 * KP;
    bf16* UrT   = WhbT + (size_t)512 * KP;
    bf16* UbT   = UrT  + (size_t)512 * KP;
    bf16* WtopT = UbT  + (size_t)512 * KP;
    bf16* WoT   = WtopT + (size_t)512 * KP;              // 896 rows
    // q-path aliases (used after p path completes):
    bf16*  qh = (bf16*)base;                             // 24576 x HP bf16
    bf16*  ql = (bf16*)(base + (size_t)QROWS * HP * 2);  // 24576 x 780 bf16

    // ---- init + fused weight prep ----
    pack_misc<<<8, 256, 0, stream>>>(Wz_b, Wh_b, Ur_b, bias4, out);
    hipMemsetAsync(pl, 0, (size_t)PROWS * 4, stream);
    prep_w<<<(BTROWS * KP + 255) / 256, 256, 0, stream>>>(Wz_w, Wh_w, Wr_w, U_w,
                                                          W_w, Wo_w, Ur_w, BT);

    // ---- embedding gather + fused per-node precompute (one GEMM, N=1800) ----
    gather_x<<<(24 * 1024 * 225 + 255) / 256, 256, 0, stream>>>(emb, wid, x_all);
    gemm128_pre<<<(QROWS / 128) * 15, 256, 0, stream>>>(x_all, BT4, Xz, bias4);

    tv_gemm<<<dim3(2, 1024), 256, 0, stream>>>(tv, W_w + 450*450, W_b, Qtv);
    tv_gemm<<<dim3(2, 1024), 256, 0, stream>>>(tv, U_w + 900*450, U_b, Ptv);

    // ---- barrier-free full scan: one launch, 128 blocks x 1024 thr ----
    scan_full<<<SROWS / 16, 1024, 0, stream>>>(hs, WzbT, WhbT, UrT, Xz, Xh, Xr);
    hv_fixup<<<(22 * SLOT + 255) / 256, 256, 0, stream>>>(hs);

    // ---- p path (before q aliases X blocks / hs) ----
    p_root<<<1024, 256, 0, stream>>>(XUa, Ptv, Us_w, pl);
    p_gemm128<<<(PROWS - 1024) / 128 * 4, 256, 0, stream>>>(hs, UbT, XUa, Ptv, Us_w, pl);
    p_final<<<PROWS / 256, 256, 0, stream>>>(pl, Us_b, out);

    // ---- q path (qh over Xz/Xh; ql over Xr/XUa/hs-head) ----
    q_root<<<(1024 * H + 255) / 256, 256, 0, stream>>>(Qtv, qh);
    gemm128<bf16><<<(NF * 1024 / 128) * 4, 256, 0, stream>>>(hs, HP, WtopT, H, 4,
                                                             qh + (size_t)1024 * HP, HP,
                                                             (const float*)nullptr, Qtv, H, 1);
    gemm128<bf16><<<(QROWS / 128) * 7, 256, 0, stream>>>(qh, HP, WoT, V, 7, ql, V,
                                                         Wo_b, (const float*)nullptr, H, 0);
    q_reduce<<<QBLK, 256, 0, stream>>>(ql, wid, qred);
    q_final<<<1, 256, 0, stream>>>(qred, out);

    (void)in_sizes; (void)n_in; (void)out_size; (void)ws_size;
}